// Round 1
// baseline (578.446 us; speedup 1.0000x reference)
//
#include <hip/hip_runtime.h>

#define N_NODES 50000
#define E_EDGES 800000
#define IN_DIM  512
#define HID     256
#define OUTD    64

typedef unsigned int uint;
typedef unsigned short ushort;

using short8 = __attribute__((ext_vector_type(8))) short;
using f32x4  = __attribute__((ext_vector_type(4))) float;

__device__ __forceinline__ ushort f2bf(float f) {
    union { float f; uint u; } v; v.f = f;
    uint u = v.u;
    // round-to-nearest-even
    uint r = (u + 0x7FFFu + ((u >> 16) & 1u)) >> 16;
    return (ushort)r;
}

__device__ __forceinline__ float bf2f(ushort h) {
    union { uint u; float f; } v; v.u = ((uint)h) << 16;
    return v.f;
}

// ---------------------------------------------------------------- CSR build
__global__ void zero_i32(int* p, int n) {
    int i = blockIdx.x * 256 + threadIdx.x;
    if (i < n) p[i] = 0;
}

__global__ void hist_k(const int* __restrict__ rows, int* __restrict__ cnt) {
    int e = blockIdx.x * 256 + threadIdx.x;
    if (e < E_EDGES) atomicAdd(&cnt[rows[e]], 1);
}

__global__ __launch_bounds__(1024) void scan_k(const int* __restrict__ cnt,
                                               int* __restrict__ row_ptr,
                                               int* __restrict__ row_cur) {
    __shared__ int wsum[16];
    __shared__ int woff[16];
    int tid = threadIdx.x;
    const int chunk = (N_NODES + 1023) / 1024;  // 49
    int base = tid * chunk;
    int lim  = base + chunk; if (lim > N_NODES) lim = N_NODES;
    int s = 0;
    for (int i = base; i < lim; i++) s += cnt[i];
    // wave inclusive scan
    int incl = s;
    #pragma unroll
    for (int d = 1; d < 64; d <<= 1) {
        int t = __shfl_up(incl, d, 64);
        if ((tid & 63) >= d) incl += t;
    }
    if ((tid & 63) == 63) wsum[tid >> 6] = incl;
    __syncthreads();
    if (tid == 0) {
        int run = 0;
        for (int w = 0; w < 16; w++) { woff[w] = run; run += wsum[w]; }
        row_ptr[N_NODES] = run;  // == E
    }
    __syncthreads();
    int off = woff[tid >> 6] + (incl - s);  // exclusive offset for this thread
    for (int i = base; i < lim; i++) {
        row_ptr[i] = off;
        row_cur[i] = off;
        off += cnt[i];
    }
}

__global__ void scatter_k(const int* __restrict__ rows, const int* __restrict__ cols,
                          const float* __restrict__ vals, int* __restrict__ row_cur,
                          int* __restrict__ col_s, float* __restrict__ val_s) {
    int e = blockIdx.x * 256 + threadIdx.x;
    if (e < E_EDGES) {
        int r = rows[e];
        int p = atomicAdd(&row_cur[r], 1);
        col_s[p] = cols[e];
        val_s[p] = vals[e];
    }
}

// ---------------------------------------------------------------- GEMM (MFMA)
// C[M,N](bf16) = A[M,K] * B[K,N](fp32)   A is fp32 or bf16 per template.
// Tiles: BM=64, BN=64, BK=32. Block = 256 thr = 4 waves; wave w owns rows
// [w*16, w*16+16) of the tile, all 4 n-subtiles.
template <bool A_BF16>
__global__ __launch_bounds__(256) void gemm_mfma(const float* __restrict__ Af,
                                                 const ushort* __restrict__ Ab,
                                                 const float* __restrict__ B,
                                                 ushort* __restrict__ C,
                                                 int M, int N, int K) {
    const int LDA = 40;  // bf16 elems per LDS row (32 + 8 pad), 80 B
    __shared__ ushort As[64 * 40];
    __shared__ ushort Bs[64 * 40];

    const int tid  = threadIdx.x;
    const int lane = tid & 63;
    const int wave = tid >> 6;
    const int quad = lane >> 4;
    const int l15  = lane & 15;

    const int row0 = blockIdx.x * 64;
    const int col0 = blockIdx.y * 64;

    f32x4 acc[4] = {};

    const int a_row = tid >> 2;  // 0..63
    const int a_kb  = tid & 3;   // 0..3, 8 k each
    const int b_n   = tid & 63;  // 0..63
    const int b_kb  = tid >> 6;  // 0..3

    for (int k0 = 0; k0 < K; k0 += 32) {
        // ---- stage A tile (64 rows x 32 k) as bf16
        {
            int gr = row0 + a_row;
            uint4 q;
            if (gr < M) {
                if (A_BF16) {
                    q = *(const uint4*)(Ab + (size_t)gr * K + k0 + a_kb * 8);
                } else {
                    const float* pa = Af + (size_t)gr * K + k0 + a_kb * 8;
                    float4 f0 = *(const float4*)pa;
                    float4 f1 = *(const float4*)(pa + 4);
                    q.x = (uint)f2bf(f0.x) | ((uint)f2bf(f0.y) << 16);
                    q.y = (uint)f2bf(f0.z) | ((uint)f2bf(f0.w) << 16);
                    q.z = (uint)f2bf(f1.x) | ((uint)f2bf(f1.y) << 16);
                    q.w = (uint)f2bf(f1.z) | ((uint)f2bf(f1.w) << 16);
                }
            } else {
                q = make_uint4(0, 0, 0, 0);
            }
            *(uint4*)&As[a_row * LDA + a_kb * 8] = q;
        }
        // ---- stage B tile transposed: Bs[n][k]  (B is [K,N] row-major)
        {
            int gn = col0 + b_n;
            ushort t[8];
            #pragma unroll
            for (int j = 0; j < 8; j++) {
                t[j] = f2bf(B[(size_t)(k0 + b_kb * 8 + j) * N + gn]);
            }
            uint4 q;
            q.x = (uint)t[0] | ((uint)t[1] << 16);
            q.y = (uint)t[2] | ((uint)t[3] << 16);
            q.z = (uint)t[4] | ((uint)t[5] << 16);
            q.w = (uint)t[6] | ((uint)t[7] << 16);
            *(uint4*)&Bs[b_n * LDA + b_kb * 8] = q;
        }
        __syncthreads();
        // ---- MFMA: A frag A[m=l15][k=quad*8+j], B frag B[k=quad*8+j][n=l15]
        short8 a = *(const short8*)&As[(wave * 16 + l15) * LDA + quad * 8];
        #pragma unroll
        for (int j = 0; j < 4; j++) {
            short8 b = *(const short8*)&Bs[(j * 16 + l15) * LDA + quad * 8];
            acc[j] = __builtin_amdgcn_mfma_f32_16x16x32_bf16(a, b, acc[j], 0, 0, 0);
        }
        __syncthreads();
    }

    // ---- epilogue: C/D layout col=lane&15, row=quad*4+reg
    #pragma unroll
    for (int j = 0; j < 4; j++) {
        #pragma unroll
        for (int r = 0; r < 4; r++) {
            int grow = row0 + wave * 16 + quad * 4 + r;
            int gcol = col0 + j * 16 + l15;
            if (grow < M) C[(size_t)grow * N + gcol] = f2bf(acc[j][r]);
        }
    }
}

// ---------------------------------------------------------------- SpMM 1
// h[r,:256] = relu(b1 + sum_e val_e * h0[col_e,:256]); wave per row, lane = 4 dims
__global__ __launch_bounds__(256) void spmm1_k(const int* __restrict__ row_ptr,
                                               const int* __restrict__ col_s,
                                               const float* __restrict__ val_s,
                                               const ushort* __restrict__ h0,
                                               const float* __restrict__ b1,
                                               ushort* __restrict__ h) {
    int wave = threadIdx.x >> 6;
    int lane = threadIdx.x & 63;
    int r = blockIdx.x * 4 + wave;
    if (r >= N_NODES) return;
    int s = row_ptr[r], e = row_ptr[r + 1];
    float a0 = 0.f, a1 = 0.f, a2 = 0.f, a3 = 0.f;
    for (int i = s; i < e; i++) {
        int c = col_s[i];
        float v = val_s[i];
        ushort4 q = *(const ushort4*)(h0 + (size_t)c * HID + lane * 4);
        a0 += v * bf2f(q.x);
        a1 += v * bf2f(q.y);
        a2 += v * bf2f(q.z);
        a3 += v * bf2f(q.w);
    }
    float4 bb = *(const float4*)(b1 + lane * 4);
    a0 += bb.x; a1 += bb.y; a2 += bb.z; a3 += bb.w;
    a0 = fmaxf(a0, 0.f); a1 = fmaxf(a1, 0.f); a2 = fmaxf(a2, 0.f); a3 = fmaxf(a3, 0.f);
    ushort4 o;
    o.x = f2bf(a0); o.y = f2bf(a1); o.z = f2bf(a2); o.w = f2bf(a3);
    *(ushort4*)(h + (size_t)r * HID + lane * 4) = o;
}

// ---------------------------------------------------------------- SpMM 2
// out[r,:64] = b2 + sum_e val_e * h2[col_e,:64]; wave per row, lane = 1 dim
__global__ __launch_bounds__(256) void spmm2_k(const int* __restrict__ row_ptr,
                                               const int* __restrict__ col_s,
                                               const float* __restrict__ val_s,
                                               const ushort* __restrict__ h2,
                                               const float* __restrict__ b2,
                                               float* __restrict__ out) {
    int wave = threadIdx.x >> 6;
    int lane = threadIdx.x & 63;
    int r = blockIdx.x * 4 + wave;
    if (r >= N_NODES) return;
    int s = row_ptr[r], e = row_ptr[r + 1];
    float acc = 0.f;
    for (int i = s; i < e; i++) {
        int c = col_s[i];
        float v = val_s[i];
        acc += v * bf2f(h2[(size_t)c * OUTD + lane]);
    }
    out[(size_t)r * OUTD + lane] = acc + b2[lane];
}

// ---------------------------------------------------------------- launch
extern "C" void kernel_launch(void* const* d_in, const int* in_sizes, int n_in,
                              void* d_out, int out_size, void* d_ws, size_t ws_size,
                              hipStream_t stream) {
    const float* x    = (const float*)d_in[0];
    const int*   rows = (const int*)d_in[1];
    const int*   cols = (const int*)d_in[2];
    const float* vals = (const float*)d_in[3];
    const float* W1   = (const float*)d_in[4];
    const float* b1   = (const float*)d_in[5];
    const float* W2   = (const float*)d_in[6];
    const float* b2   = (const float*)d_in[7];
    float* out = (float*)d_out;

    char* ws = (char*)d_ws;
    size_t off = 0;
    auto alloc = [&](size_t bytes) {
        char* p = ws + off;
        off = (off + bytes + 255) & ~(size_t)255;
        return p;
    };
    ushort* h0    = (ushort*)alloc((size_t)N_NODES * HID * 2);
    ushort* h     = (ushort*)alloc((size_t)N_NODES * HID * 2);
    ushort* h2    = (ushort*)alloc((size_t)N_NODES * OUTD * 2);
    int*    cnt   = (int*)alloc((N_NODES + 1) * 4);
    int*    rptr  = (int*)alloc((N_NODES + 1) * 4);
    int*    rcur  = (int*)alloc((N_NODES + 1) * 4);
    int*    col_s = (int*)alloc((size_t)E_EDGES * 4);
    float*  val_s = (float*)alloc((size_t)E_EDGES * 4);

    // CSR build (reused by both SpMMs)
    zero_i32<<<(N_NODES + 1 + 255) / 256, 256, 0, stream>>>(cnt, N_NODES + 1);
    hist_k<<<(E_EDGES + 255) / 256, 256, 0, stream>>>(rows, cnt);
    scan_k<<<1, 1024, 0, stream>>>(cnt, rptr, rcur);
    scatter_k<<<(E_EDGES + 255) / 256, 256, 0, stream>>>(rows, cols, vals, rcur, col_s, val_s);

    // layer 1
    gemm_mfma<false><<<dim3((N_NODES + 63) / 64, HID / 64), 256, 0, stream>>>(
        x, nullptr, W1, h0, N_NODES, HID, IN_DIM);
    spmm1_k<<<(N_NODES + 3) / 4, 256, 0, stream>>>(rptr, col_s, val_s, h0, b1, h);

    // layer 2
    gemm_mfma<true><<<dim3((N_NODES + 63) / 64, OUTD / 64), 256, 0, stream>>>(
        nullptr, h, W2, h2, N_NODES, OUTD, HID);
    spmm2_k<<<(N_NODES + 3) / 4, 256, 0, stream>>>(rptr, col_s, val_s, h2, b2, out);
}

// Round 2
// 476.600 us; speedup vs baseline: 1.2137x; 1.2137x over previous
//
#include <hip/hip_runtime.h>

#define N_NODES 50000
#define E_EDGES 800000
#define IN_DIM  512
#define HID     256
#define OUTD    64

#define SCAN_NB  49          // ceil(50000/1024)
#define PAD_N    (SCAN_NB * 1024)  // 50176

typedef unsigned int uint;
typedef unsigned short ushort;

using short8 = __attribute__((ext_vector_type(8))) short;
using f32x4  = __attribute__((ext_vector_type(4))) float;

__device__ __forceinline__ ushort f2bf(float f) {
    union { float f; uint u; } v; v.f = f;
    uint u = v.u;
    uint r = (u + 0x7FFFu + ((u >> 16) & 1u)) >> 16;  // RNE
    return (ushort)r;
}

__device__ __forceinline__ float bf2f(ushort h) {
    union { uint u; float f; } v; v.u = ((uint)h) << 16;
    return v.f;
}

// ---------------------------------------------------------------- CSR build
__global__ void zero_i32(int* p, int n) {
    int i = blockIdx.x * 256 + threadIdx.x;
    if (i < n) p[i] = 0;
}

__global__ void hist_k(const int* __restrict__ rows, int* __restrict__ cnt) {
    int e = blockIdx.x * 256 + threadIdx.x;
    if (e < E_EDGES) atomicAdd(&cnt[rows[e]], 1);
}

// phase 1: per-block (1024 counts) sums
__global__ __launch_bounds__(256) void scan_part_k(const int* __restrict__ cnt,
                                                   int* __restrict__ bsum) {
    __shared__ int wsum[4];
    int tid  = threadIdx.x;
    int lane = tid & 63;
    int wave = tid >> 6;
    int4 q = *(const int4*)(cnt + blockIdx.x * 1024 + tid * 4);
    int s = q.x + q.y + q.z + q.w;
    #pragma unroll
    for (int d = 32; d > 0; d >>= 1) s += __shfl_down(s, d, 64);
    if (lane == 0) wsum[wave] = s;
    __syncthreads();
    if (tid == 0) bsum[blockIdx.x] = wsum[0] + wsum[1] + wsum[2] + wsum[3];
}

// phase 2: exclusive scan of the 49 block sums (one wave)
__global__ __launch_bounds__(64) void scan_bsum_k(const int* __restrict__ bsum,
                                                  int* __restrict__ boff) {
    int tid = threadIdx.x;
    int v = (tid < SCAN_NB) ? bsum[tid] : 0;
    int incl = v;
    #pragma unroll
    for (int d = 1; d < 64; d <<= 1) {
        int t = __shfl_up(incl, d, 64);
        if (tid >= d) incl += t;
    }
    if (tid < SCAN_NB) boff[tid] = incl - v;
}

// phase 3: intra-block exclusive scan + block offset -> row_ptr / row_cur
__global__ __launch_bounds__(256) void scan_final_k(const int* __restrict__ cnt,
                                                    const int* __restrict__ boff,
                                                    int* __restrict__ row_ptr,
                                                    int* __restrict__ row_cur) {
    __shared__ int wsum[4];
    __shared__ int woff[4];
    int tid  = threadIdx.x;
    int lane = tid & 63;
    int wave = tid >> 6;
    int base = blockIdx.x * 1024 + tid * 4;
    int4 q = *(const int4*)(cnt + base);
    int s = q.x + q.y + q.z + q.w;
    int incl = s;
    #pragma unroll
    for (int d = 1; d < 64; d <<= 1) {
        int t = __shfl_up(incl, d, 64);
        if (lane >= d) incl += t;
    }
    if (lane == 63) wsum[wave] = incl;
    __syncthreads();
    if (tid == 0) {
        int run = 0;
        #pragma unroll
        for (int w = 0; w < 4; w++) { woff[w] = run; run += wsum[w]; }
    }
    __syncthreads();
    int off = boff[blockIdx.x] + woff[wave] + (incl - s);  // exclusive
    int4 o;
    o.x = off;
    o.y = off + q.x;
    o.z = o.y + q.y;
    o.w = o.z + q.z;
    *(int4*)(row_ptr + base) = o;
    *(int4*)(row_cur + base) = o;
    if (blockIdx.x == 0 && tid == 0) row_ptr[N_NODES] = E_EDGES;
}

__global__ void scatter_k(const int* __restrict__ rows, const int* __restrict__ cols,
                          const float* __restrict__ vals, int* __restrict__ row_cur,
                          int* __restrict__ col_s, float* __restrict__ val_s) {
    int e = blockIdx.x * 256 + threadIdx.x;
    if (e < E_EDGES) {
        int r = rows[e];
        int p = atomicAdd(&row_cur[r], 1);
        col_s[p] = cols[e];
        val_s[p] = vals[e];
    }
}

// ---------------------------------------------------------------- GEMM (MFMA)
// C[M,N](bf16) = A[M,K] * B[K,N](fp32)   A is fp32 or bf16 per template.
// Tiles: BM=64, BN=64, BK=32. Block = 256 thr = 4 waves.
template <bool A_BF16>
__global__ __launch_bounds__(256) void gemm_mfma(const float* __restrict__ Af,
                                                 const ushort* __restrict__ Ab,
                                                 const float* __restrict__ B,
                                                 ushort* __restrict__ C,
                                                 int M, int N, int K) {
    const int LDA = 40;  // bf16 elems per LDS row (32 + 8 pad), 80 B
    __shared__ ushort As[64 * 40];
    __shared__ ushort Bs[64 * 40];

    const int tid  = threadIdx.x;
    const int lane = tid & 63;
    const int wave = tid >> 6;
    const int quad = lane >> 4;
    const int l15  = lane & 15;

    const int row0 = blockIdx.x * 64;
    const int col0 = blockIdx.y * 64;

    f32x4 acc[4] = {};

    const int a_row = tid >> 2;  // 0..63
    const int a_kb  = tid & 3;   // 0..3, 8 k each
    const int b_n   = tid & 63;  // 0..63
    const int b_kb  = tid >> 6;  // 0..3

    for (int k0 = 0; k0 < K; k0 += 32) {
        {
            int gr = row0 + a_row;
            uint4 q;
            if (gr < M) {
                if (A_BF16) {
                    q = *(const uint4*)(Ab + (size_t)gr * K + k0 + a_kb * 8);
                } else {
                    const float* pa = Af + (size_t)gr * K + k0 + a_kb * 8;
                    float4 f0 = *(const float4*)pa;
                    float4 f1 = *(const float4*)(pa + 4);
                    q.x = (uint)f2bf(f0.x) | ((uint)f2bf(f0.y) << 16);
                    q.y = (uint)f2bf(f0.z) | ((uint)f2bf(f0.w) << 16);
                    q.z = (uint)f2bf(f1.x) | ((uint)f2bf(f1.y) << 16);
                    q.w = (uint)f2bf(f1.z) | ((uint)f2bf(f1.w) << 16);
                }
            } else {
                q = make_uint4(0, 0, 0, 0);
            }
            *(uint4*)&As[a_row * LDA + a_kb * 8] = q;
        }
        {
            int gn = col0 + b_n;
            ushort t[8];
            #pragma unroll
            for (int j = 0; j < 8; j++) {
                t[j] = f2bf(B[(size_t)(k0 + b_kb * 8 + j) * N + gn]);
            }
            uint4 q;
            q.x = (uint)t[0] | ((uint)t[1] << 16);
            q.y = (uint)t[2] | ((uint)t[3] << 16);
            q.z = (uint)t[4] | ((uint)t[5] << 16);
            q.w = (uint)t[6] | ((uint)t[7] << 16);
            *(uint4*)&Bs[b_n * LDA + b_kb * 8] = q;
        }
        __syncthreads();
        short8 a = *(const short8*)&As[(wave * 16 + l15) * LDA + quad * 8];
        #pragma unroll
        for (int j = 0; j < 4; j++) {
            short8 b = *(const short8*)&Bs[(j * 16 + l15) * LDA + quad * 8];
            acc[j] = __builtin_amdgcn_mfma_f32_16x16x32_bf16(a, b, acc[j], 0, 0, 0);
        }
        __syncthreads();
    }

    #pragma unroll
    for (int j = 0; j < 4; j++) {
        #pragma unroll
        for (int r = 0; r < 4; r++) {
            int grow = row0 + wave * 16 + quad * 4 + r;
            int gcol = col0 + j * 16 + l15;
            if (grow < M) C[(size_t)grow * N + gcol] = f2bf(acc[j][r]);
        }
    }
}

// ---------------------------------------------------------------- SpMM 1
__global__ __launch_bounds__(256) void spmm1_k(const int* __restrict__ row_ptr,
                                               const int* __restrict__ col_s,
                                               const float* __restrict__ val_s,
                                               const ushort* __restrict__ h0,
                                               const float* __restrict__ b1,
                                               ushort* __restrict__ h) {
    int wave = threadIdx.x >> 6;
    int lane = threadIdx.x & 63;
    int r = blockIdx.x * 4 + wave;
    if (r >= N_NODES) return;
    int s = row_ptr[r], e = row_ptr[r + 1];
    float a0 = 0.f, a1 = 0.f, a2 = 0.f, a3 = 0.f;
    for (int i = s; i < e; i++) {
        int c = col_s[i];
        float v = val_s[i];
        ushort4 q = *(const ushort4*)(h0 + (size_t)c * HID + lane * 4);
        a0 += v * bf2f(q.x);
        a1 += v * bf2f(q.y);
        a2 += v * bf2f(q.z);
        a3 += v * bf2f(q.w);
    }
    float4 bb = *(const float4*)(b1 + lane * 4);
    a0 += bb.x; a1 += bb.y; a2 += bb.z; a3 += bb.w;
    a0 = fmaxf(a0, 0.f); a1 = fmaxf(a1, 0.f); a2 = fmaxf(a2, 0.f); a3 = fmaxf(a3, 0.f);
    ushort4 o;
    o.x = f2bf(a0); o.y = f2bf(a1); o.z = f2bf(a2); o.w = f2bf(a3);
    *(ushort4*)(h + (size_t)r * HID + lane * 4) = o;
}

// ---------------------------------------------------------------- SpMM 2
__global__ __launch_bounds__(256) void spmm2_k(const int* __restrict__ row_ptr,
                                               const int* __restrict__ col_s,
                                               const float* __restrict__ val_s,
                                               const ushort* __restrict__ h2,
                                               const float* __restrict__ b2,
                                               float* __restrict__ out) {
    int wave = threadIdx.x >> 6;
    int lane = threadIdx.x & 63;
    int r = blockIdx.x * 4 + wave;
    if (r >= N_NODES) return;
    int s = row_ptr[r], e = row_ptr[r + 1];
    float acc = 0.f;
    for (int i = s; i < e; i++) {
        int c = col_s[i];
        float v = val_s[i];
        acc += v * bf2f(h2[(size_t)c * OUTD + lane]);
    }
    out[(size_t)r * OUTD + lane] = acc + b2[lane];
}

// ---------------------------------------------------------------- launch
extern "C" void kernel_launch(void* const* d_in, const int* in_sizes, int n_in,
                              void* d_out, int out_size, void* d_ws, size_t ws_size,
                              hipStream_t stream) {
    const float* x    = (const float*)d_in[0];
    const int*   rows = (const int*)d_in[1];
    const int*   cols = (const int*)d_in[2];
    const float* vals = (const float*)d_in[3];
    const float* W1   = (const float*)d_in[4];
    const float* b1   = (const float*)d_in[5];
    const float* W2   = (const float*)d_in[6];
    const float* b2   = (const float*)d_in[7];
    float* out = (float*)d_out;

    char* ws = (char*)d_ws;
    size_t off = 0;
    auto alloc = [&](size_t bytes) {
        char* p = ws + off;
        off = (off + bytes + 255) & ~(size_t)255;
        return p;
    };
    ushort* h0    = (ushort*)alloc((size_t)N_NODES * HID * 2);
    ushort* h     = (ushort*)alloc((size_t)N_NODES * HID * 2);
    ushort* h2    = (ushort*)alloc((size_t)N_NODES * OUTD * 2);
    int*    cnt   = (int*)alloc((PAD_N) * 4);          // padded, zeroed
    int*    rptr  = (int*)alloc((PAD_N + 1) * 4);      // padded (writes past N harmless)
    int*    rcur  = (int*)alloc((PAD_N) * 4);
    int*    bsum  = (int*)alloc(SCAN_NB * 4);
    int*    boff  = (int*)alloc(SCAN_NB * 4);
    int*    col_s = (int*)alloc((size_t)E_EDGES * 4);
    float*  val_s = (float*)alloc((size_t)E_EDGES * 4);

    // CSR build (reused by both SpMMs)
    zero_i32<<<(PAD_N + 255) / 256, 256, 0, stream>>>(cnt, PAD_N);
    hist_k<<<(E_EDGES + 255) / 256, 256, 0, stream>>>(rows, cnt);
    scan_part_k<<<SCAN_NB, 256, 0, stream>>>(cnt, bsum);
    scan_bsum_k<<<1, 64, 0, stream>>>(bsum, boff);
    scan_final_k<<<SCAN_NB, 256, 0, stream>>>(cnt, boff, rptr, rcur);
    scatter_k<<<(E_EDGES + 255) / 256, 256, 0, stream>>>(rows, cols, vals, rcur, col_s, val_s);

    // layer 1
    gemm_mfma<false><<<dim3((N_NODES + 63) / 64, HID / 64), 256, 0, stream>>>(
        x, nullptr, W1, h0, N_NODES, HID, IN_DIM);
    spmm1_k<<<(N_NODES + 3) / 4, 256, 0, stream>>>(rptr, col_s, val_s, h0, b1, h);

    // layer 2
    gemm_mfma<true><<<dim3((N_NODES + 63) / 64, OUTD / 64), 256, 0, stream>>>(
        nullptr, h, W2, h2, N_NODES, OUTD, HID);
    spmm2_k<<<(N_NODES + 3) / 4, 256, 0, stream>>>(rptr, col_s, val_s, h2, b2, out);
}

// Round 5
// 401.726 us; speedup vs baseline: 1.4399x; 1.1864x over previous
//
#include <hip/hip_runtime.h>

#define N_NODES 50000
#define E_EDGES 800000
#define IN_DIM  512
#define HID     256
#define OUTD    64

#define SCAN_NB  49                // ceil(50000/1024)
#define PAD_N    (SCAN_NB * 1024)  // 50176

typedef unsigned int uint;
typedef unsigned short ushort;

using short8 = __attribute__((ext_vector_type(8))) short;
using f32x4  = __attribute__((ext_vector_type(4))) float;

__device__ __forceinline__ ushort f2bf(float f) {
    union { float f; uint u; } v; v.f = f;
    uint u = v.u;
    uint r = (u + 0x7FFFu + ((u >> 16) & 1u)) >> 16;  // RNE
    return (ushort)r;
}

__device__ __forceinline__ float bf2f(ushort h) {
    union { uint u; float f; } v; v.u = ((uint)h) << 16;
    return v.f;
}

// ---------------------------------------------------------------- CSR build
__global__ void zero_i32(int* p, int n) {
    int i = blockIdx.x * 256 + threadIdx.x;
    if (i < n) p[i] = 0;
}

__global__ void hist_k(const int* __restrict__ rows, int* __restrict__ cnt) {
    int e = blockIdx.x * 256 + threadIdx.x;
    if (e < E_EDGES) atomicAdd(&cnt[rows[e]], 1);
}

__global__ __launch_bounds__(256) void scan_part_k(const int* __restrict__ cnt,
                                                   int* __restrict__ bsum) {
    __shared__ int wsum[4];
    int tid  = threadIdx.x;
    int lane = tid & 63;
    int wave = tid >> 6;
    int4 q = *(const int4*)(cnt + blockIdx.x * 1024 + tid * 4);
    int s = q.x + q.y + q.z + q.w;
    #pragma unroll
    for (int d = 32; d > 0; d >>= 1) s += __shfl_down(s, d, 64);
    if (lane == 0) wsum[wave] = s;
    __syncthreads();
    if (tid == 0) bsum[blockIdx.x] = wsum[0] + wsum[1] + wsum[2] + wsum[3];
}

__global__ __launch_bounds__(64) void scan_bsum_k(const int* __restrict__ bsum,
                                                  int* __restrict__ boff) {
    int tid = threadIdx.x;
    int v = (tid < SCAN_NB) ? bsum[tid] : 0;
    int incl = v;
    #pragma unroll
    for (int d = 1; d < 64; d <<= 1) {
        int t = __shfl_up(incl, d, 64);
        if (tid >= d) incl += t;
    }
    if (tid < SCAN_NB) boff[tid] = incl - v;
}

__global__ __launch_bounds__(256) void scan_final_k(const int* __restrict__ cnt,
                                                    const int* __restrict__ boff,
                                                    int* __restrict__ row_ptr,
                                                    int* __restrict__ row_cur) {
    __shared__ int wsum[4];
    __shared__ int woff[4];
    int tid  = threadIdx.x;
    int lane = tid & 63;
    int wave = tid >> 6;
    int base = blockIdx.x * 1024 + tid * 4;
    int4 q = *(const int4*)(cnt + base);
    int s = q.x + q.y + q.z + q.w;
    int incl = s;
    #pragma unroll
    for (int d = 1; d < 64; d <<= 1) {
        int t = __shfl_up(incl, d, 64);
        if (lane >= d) incl += t;
    }
    if (lane == 63) wsum[wave] = incl;
    __syncthreads();
    if (tid == 0) {
        int run = 0;
        #pragma unroll
        for (int w = 0; w < 4; w++) { woff[w] = run; run += wsum[w]; }
    }
    __syncthreads();
    int off = boff[blockIdx.x] + woff[wave] + (incl - s);
    int4 o;
    o.x = off;
    o.y = off + q.x;
    o.z = o.y + q.y;
    o.w = o.z + q.z;
    *(int4*)(row_ptr + base) = o;
    *(int4*)(row_cur + base) = o;
    if (blockIdx.x == 0 && tid == 0) row_ptr[N_NODES] = E_EDGES;
}

__global__ void scatter_k(const int* __restrict__ rows, const int* __restrict__ cols,
                          const float* __restrict__ vals, int* __restrict__ row_cur,
                          int* __restrict__ col_s, float* __restrict__ val_s) {
    int e = blockIdx.x * 256 + threadIdx.x;
    if (e < E_EDGES) {
        int r = rows[e];
        int p = atomicAdd(&row_cur[r], 1);
        col_s[p] = cols[e];
        val_s[p] = vals[e];
    }
}

// ---------------------------------------------------------------- GEMM (MFMA)
template <bool A_BF16>
__global__ __launch_bounds__(256) void gemm_mfma(const float* __restrict__ Af,
                                                 const ushort* __restrict__ Ab,
                                                 const float* __restrict__ B,
                                                 ushort* __restrict__ C,
                                                 int M, int N, int K) {
    const int LDA = 40;
    __shared__ ushort As[64 * 40];
    __shared__ ushort Bs[64 * 40];

    const int tid  = threadIdx.x;
    const int lane = tid & 63;
    const int wave = tid >> 6;
    const int quad = lane >> 4;
    const int l15  = lane & 15;

    const int row0 = blockIdx.x * 64;
    const int col0 = blockIdx.y * 64;

    f32x4 acc[4] = {};

    const int a_row = tid >> 2;
    const int a_kb  = tid & 3;
    const int b_n   = tid & 63;
    const int b_kb  = tid >> 6;

    for (int k0 = 0; k0 < K; k0 += 32) {
        {
            int gr = row0 + a_row;
            uint4 q;
            if (gr < M) {
                if (A_BF16) {
                    q = *(const uint4*)(Ab + (size_t)gr * K + k0 + a_kb * 8);
                } else {
                    const float* pa = Af + (size_t)gr * K + k0 + a_kb * 8;
                    float4 f0 = *(const float4*)pa;
                    float4 f1 = *(const float4*)(pa + 4);
                    q.x = (uint)f2bf(f0.x) | ((uint)f2bf(f0.y) << 16);
                    q.y = (uint)f2bf(f0.z) | ((uint)f2bf(f0.w) << 16);
                    q.z = (uint)f2bf(f1.x) | ((uint)f2bf(f1.y) << 16);
                    q.w = (uint)f2bf(f1.z) | ((uint)f2bf(f1.w) << 16);
                }
            } else {
                q = make_uint4(0, 0, 0, 0);
            }
            *(uint4*)&As[a_row * LDA + a_kb * 8] = q;
        }
        {
            int gn = col0 + b_n;
            ushort t[8];
            #pragma unroll
            for (int j = 0; j < 8; j++) {
                t[j] = f2bf(B[(size_t)(k0 + b_kb * 8 + j) * N + gn]);
            }
            uint4 q;
            q.x = (uint)t[0] | ((uint)t[1] << 16);
            q.y = (uint)t[2] | ((uint)t[3] << 16);
            q.z = (uint)t[4] | ((uint)t[5] << 16);
            q.w = (uint)t[6] | ((uint)t[7] << 16);
            *(uint4*)&Bs[b_n * LDA + b_kb * 8] = q;
        }
        __syncthreads();
        short8 a = *(const short8*)&As[(wave * 16 + l15) * LDA + quad * 8];
        #pragma unroll
        for (int j = 0; j < 4; j++) {
            short8 b = *(const short8*)&Bs[(j * 16 + l15) * LDA + quad * 8];
            acc[j] = __builtin_amdgcn_mfma_f32_16x16x32_bf16(a, b, acc[j], 0, 0, 0);
        }
        __syncthreads();
    }

    #pragma unroll
    for (int j = 0; j < 4; j++) {
        #pragma unroll
        for (int r = 0; r < 4; r++) {
            int grow = row0 + wave * 16 + quad * 4 + r;
            int gcol = col0 + j * 16 + l15;
            if (grow < M) C[(size_t)grow * N + gcol] = f2bf(acc[j][r]);
        }
    }
}

// ---------------------------------------------------------------- SpMM 1
// wave per row; lane covers dims [lane*4, lane*4+4). Edge loop unrolled x4:
// 4 independent 512B gathers in flight to break the latency chain.
__global__ __launch_bounds__(256) void spmm1_k(const int* __restrict__ row_ptr,
                                               const int* __restrict__ col_s,
                                               const float* __restrict__ val_s,
                                               const ushort* __restrict__ h0,
                                               const float* __restrict__ b1,
                                               ushort* __restrict__ h) {
    int wave = threadIdx.x >> 6;
    int lane = threadIdx.x & 63;
    int r = blockIdx.x * 4 + wave;
    if (r >= N_NODES) return;
    int s = row_ptr[r];
    int e = row_ptr[r + 1];
    const ushort* hp = h0 + (size_t)lane * 4;
    float a0 = 0.f, a1 = 0.f, a2 = 0.f, a3 = 0.f;
    int i = s;
    for (; i + 4 <= e; i += 4) {
        int c0 = col_s[i];
        int c1 = col_s[i + 1];
        int c2 = col_s[i + 2];
        int c3 = col_s[i + 3];
        float v0 = val_s[i];
        float v1 = val_s[i + 1];
        float v2 = val_s[i + 2];
        float v3 = val_s[i + 3];
        ushort4 q0 = *(const ushort4*)(hp + (size_t)c0 * HID);
        ushort4 q1 = *(const ushort4*)(hp + (size_t)c1 * HID);
        ushort4 q2 = *(const ushort4*)(hp + (size_t)c2 * HID);
        ushort4 q3 = *(const ushort4*)(hp + (size_t)c3 * HID);
        a0 += v0 * bf2f(q0.x); a1 += v0 * bf2f(q0.y); a2 += v0 * bf2f(q0.z); a3 += v0 * bf2f(q0.w);
        a0 += v1 * bf2f(q1.x); a1 += v1 * bf2f(q1.y); a2 += v1 * bf2f(q1.z); a3 += v1 * bf2f(q1.w);
        a0 += v2 * bf2f(q2.x); a1 += v2 * bf2f(q2.y); a2 += v2 * bf2f(q2.z); a3 += v2 * bf2f(q2.w);
        a0 += v3 * bf2f(q3.x); a1 += v3 * bf2f(q3.y); a2 += v3 * bf2f(q3.z); a3 += v3 * bf2f(q3.w);
    }
    for (; i < e; i++) {
        int c = col_s[i];
        float v = val_s[i];
        ushort4 q = *(const ushort4*)(hp + (size_t)c * HID);
        a0 += v * bf2f(q.x); a1 += v * bf2f(q.y); a2 += v * bf2f(q.z); a3 += v * bf2f(q.w);
    }
    float4 bb = *(const float4*)(b1 + lane * 4);
    a0 += bb.x; a1 += bb.y; a2 += bb.z; a3 += bb.w;
    a0 = fmaxf(a0, 0.f); a1 = fmaxf(a1, 0.f); a2 = fmaxf(a2, 0.f); a3 = fmaxf(a3, 0.f);
    ushort4 o;
    o.x = f2bf(a0); o.y = f2bf(a1); o.z = f2bf(a2); o.w = f2bf(a3);
    *(ushort4*)(h + (size_t)r * HID + lane * 4) = o;
}

// ---------------------------------------------------------------- SpMM 2
// wave per row; lanes = 16 dim-groups x 4 edge-slots. Each lane loads ushort4
// (8B) of h2[col_slot][dg*4..+3]; 4 edges concurrent per iteration. Per-lane
// loop bound keeps every load in-bounds (no guarded/speculative loads).
// Final cross-slot reduce via shfl_xor(16), shfl_xor(32); lanes 0..15 write.
__global__ __launch_bounds__(256) void spmm2_k(const int* __restrict__ row_ptr,
                                               const int* __restrict__ col_s,
                                               const float* __restrict__ val_s,
                                               const ushort* __restrict__ h2,
                                               const float* __restrict__ b2,
                                               float* __restrict__ out) {
    int wave = threadIdx.x >> 6;
    int lane = threadIdx.x & 63;
    int r = blockIdx.x * 4 + wave;
    if (r >= N_NODES) return;
    int s = row_ptr[r];
    int e = row_ptr[r + 1];
    int slot = lane >> 4;   // 0..3
    int dg   = lane & 15;   // dim group, 4 dims
    float a0 = 0.f, a1 = 0.f, a2 = 0.f, a3 = 0.f;
    const ushort* hp = h2 + (size_t)dg * 4;
    for (int i = s + slot; i < e; i += 4) {
        int c = col_s[i];
        float v = val_s[i];
        ushort4 q = *(const ushort4*)(hp + (size_t)c * OUTD);
        a0 += v * bf2f(q.x);
        a1 += v * bf2f(q.y);
        a2 += v * bf2f(q.z);
        a3 += v * bf2f(q.w);
    }
    #pragma unroll
    for (int m = 16; m < 64; m <<= 1) {
        a0 += __shfl_xor(a0, m, 64);
        a1 += __shfl_xor(a1, m, 64);
        a2 += __shfl_xor(a2, m, 64);
        a3 += __shfl_xor(a3, m, 64);
    }
    if (slot == 0) {
        float4 bb = *(const float4*)(b2 + dg * 4);
        float4 o;
        o.x = a0 + bb.x; o.y = a1 + bb.y; o.z = a2 + bb.z; o.w = a3 + bb.w;
        *(float4*)(out + (size_t)r * OUTD + dg * 4) = o;
    }
}

// ---------------------------------------------------------------- launch
extern "C" void kernel_launch(void* const* d_in, const int* in_sizes, int n_in,
                              void* d_out, int out_size, void* d_ws, size_t ws_size,
                              hipStream_t stream) {
    const float* x    = (const float*)d_in[0];
    const int*   rows = (const int*)d_in[1];
    const int*   cols = (const int*)d_in[2];
    const float* vals = (const float*)d_in[3];
    const float* W1   = (const float*)d_in[4];
    const float* b1   = (const float*)d_in[5];
    const float* W2   = (const float*)d_in[6];
    const float* b2   = (const float*)d_in[7];
    float* out = (float*)d_out;

    char* ws = (char*)d_ws;
    size_t off = 0;
    auto alloc = [&](size_t bytes) {
        char* p = ws + off;
        off = (off + bytes + 255) & ~(size_t)255;
        return p;
    };
    ushort* h0    = (ushort*)alloc((size_t)N_NODES * HID * 2);
    ushort* h     = (ushort*)alloc((size_t)N_NODES * HID * 2);
    ushort* h2    = (ushort*)alloc((size_t)N_NODES * OUTD * 2);
    int*    cnt   = (int*)alloc((PAD_N) * 4);
    int*    rptr  = (int*)alloc((PAD_N + 1) * 4);
    int*    rcur  = (int*)alloc((PAD_N) * 4);
    int*    bsum  = (int*)alloc(SCAN_NB * 4);
    int*    boff  = (int*)alloc(SCAN_NB * 4);
    int*    col_s = (int*)alloc((size_t)E_EDGES * 4);
    float*  val_s = (float*)alloc((size_t)E_EDGES * 4);

    zero_i32<<<(PAD_N + 255) / 256, 256, 0, stream>>>(cnt, PAD_N);
    hist_k<<<(E_EDGES + 255) / 256, 256, 0, stream>>>(rows, cnt);
    scan_part_k<<<SCAN_NB, 256, 0, stream>>>(cnt, bsum);
    scan_bsum_k<<<1, 64, 0, stream>>>(bsum, boff);
    scan_final_k<<<SCAN_NB, 256, 0, stream>>>(cnt, boff, rptr, rcur);
    scatter_k<<<(E_EDGES + 255) / 256, 256, 0, stream>>>(rows, cols, vals, rcur, col_s, val_s);

    gemm_mfma<false><<<dim3((N_NODES + 63) / 64, HID / 64), 256, 0, stream>>>(
        x, nullptr, W1, h0, N_NODES, HID, IN_DIM);
    spmm1_k<<<(N_NODES + 3) / 4, 256, 0, stream>>>(rptr, col_s, val_s, h0, b1, h);

    gemm_mfma<true><<<dim3((N_NODES + 63) / 64, OUTD / 64), 256, 0, stream>>>(
        nullptr, h, W2, h2, N_NODES, OUTD, HID);
    spmm2_k<<<(N_NODES + 3) / 4, 256, 0, stream>>>(rptr, col_s, val_s, h2, b2, out);
}